// Round 12
// baseline (2377.378 us; speedup 1.0000x reference)
//
#include <hip/hip_runtime.h>
#include <hip/hip_bf16.h>
#include <math.h>

// dims
constexpr int B_   = 2;
constexpr int L_   = 512;
constexpr int LP1  = 513;
constexpr int D_   = 512;
constexpr int H_   = 8;
constexpr int HD_  = 64;
constexpr int FF_  = 2048;
constexpr int RFFD = 32;
constexpr int RBH  = 64;
constexpr int M_   = B_ * LP1;     // 1026
constexpr float EPS_ = 1e-5f;
constexpr int NT_  = 8193;         // bias table entries over ds in [-1,1]
constexpr int QB_  = 4;            // queries per attention block
constexpr int QBLKS_ = (LP1 + QB_ - 1) / QB_;   // 129

// ws layout (floats), overlays:
constexpr size_t OFFZ   = 0;
constexpr size_t OFFX1  = OFFZ  + (size_t)M_ * D_;          // 525,312
constexpr size_t OFFQKV = OFFX1 + (size_t)M_ * D_;          // 1,050,624
constexpr size_t OFFKT  = OFFQKV + (size_t)M_ * 3 * D_;     // 2,626,560
constexpr size_t OFFA   = OFFKT + (size_t)B_ * D_ * LP1;    // 3,151,872
constexpr size_t OFFT   = OFFA + (size_t)M_ * D_;           // 3,677,184
// + NT_*8 = 65,544 -> total 3,742,728 floats = 15.0 MB

typedef __attribute__((ext_vector_type(4))) float f32x4;
typedef __attribute__((ext_vector_type(8))) __bf16 bf16x8;
typedef __attribute__((ext_vector_type(4))) __bf16 bf16x4;

__device__ __forceinline__ float gelu_exact(float x) {
    return 0.5f * x * (1.0f + erff(x * 0.70710678118654752f));
}

__device__ __forceinline__ __bf16 f2b(float f) {
    union { float f; unsigned u; } a; a.f = f;
    const unsigned r = (a.u + 0x7FFFu + ((a.u >> 16) & 1u)) >> 16;   // RNE
    union { unsigned short s; __bf16 b; } o; o.s = (unsigned short)r;
    return o.b;
}

// ---------------- bias table: table[idx][h] = biasMLP(ds(idx))[h] ----------------
__global__ void k_btab(const float* __restrict__ rff, const float* __restrict__ w1,
                       const float* __restrict__ b1, const float* __restrict__ w2,
                       const float* __restrict__ b2, float* __restrict__ table) {
    const int idx = blockIdx.x * 256 + threadIdx.x;
    if (idx >= NT_) return;
    const float ds = (float)idx * (2.0f / (NT_ - 1)) - 1.0f;
    float feat[RFFD];
    #pragma unroll
    for (int k = 0; k < RFFD; ++k) feat[k] = sinf(ds * rff[k]);
    float bh[H_];
    #pragma unroll
    for (int h = 0; h < H_; ++h) bh[h] = b2[h];
    for (int l = 0; l < RBH; ++l) {
        float acc = b1[l];
        #pragma unroll
        for (int k = 0; k < RFFD; ++k) acc += feat[k] * w1[l * RFFD + k];
        const float gl = gelu_exact(acc);
        #pragma unroll
        for (int h = 0; h < H_; ++h) bh[h] += gl * w2[h * RBH + l];
    }
    #pragma unroll
    for (int h = 0; h < H_; ++h) table[(size_t)idx * H_ + h] = bh[h];
}

// ---------------- LayerNorm: one block (256) per token ----------------
__global__ void k_ln(const float* __restrict__ x, const float* __restrict__ g,
                     const float* __restrict__ be, float* __restrict__ out) {
    const int m = blockIdx.x;
    const int t = threadIdx.x;
    __shared__ float red[256];
    const float v0 = x[(size_t)m * D_ + t];
    const float v1 = x[(size_t)m * D_ + t + 256];
    red[t] = v0 + v1;
    __syncthreads();
    for (int off = 128; off > 0; off >>= 1) {
        if (t < off) red[t] += red[t + off];
        __syncthreads();
    }
    const float mu = red[0] * (1.0f / D_);
    __syncthreads();
    const float d0 = v0 - mu, d1 = v1 - mu;
    red[t] = d0 * d0 + d1 * d1;
    __syncthreads();
    for (int off = 128; off > 0; off >>= 1) {
        if (t < off) red[t] += red[t + off];
        __syncthreads();
    }
    const float rstd = rsqrtf(red[0] * (1.0f / D_) + EPS_);
    out[(size_t)m * D_ + t]       = d0 * rstd * g[t]       + be[t];
    out[(size_t)m * D_ + t + 256] = d1 * rstd * g[t + 256] + be[t + 256];
}

// ---------------- MFMA bf16 GEMM: C = act(A @ W^T + bias) (+res) ----------------
template <int ACT, bool RES>
__global__ __launch_bounds__(256)
void k_gemm_mfma(const float* __restrict__ A, const float* __restrict__ W,
                 const float* __restrict__ bias, const float* __restrict__ res,
                 float* __restrict__ C, int M, int N, int K) {
    constexpr int BM = 64, BN = 64, BK = 32, PAD = 8;   // row stride 80B (16B-aligned)
    __shared__ __bf16 As[BM][BK + PAD];
    __shared__ __bf16 Bs[BN][BK + PAD];
    const int t    = threadIdx.x;
    const int m0   = blockIdx.y * BM;
    const int n0   = blockIdx.x * BN;
    const int wid  = t >> 6;
    const int lane = t & 63;
    const int wr   = (wid >> 1) * 32;
    const int wc   = (wid & 1) * 32;
    const int fr   = lane & 15;
    const int kg   = lane >> 4;

    f32x4 acc[2][2] = {};

    for (int k0 = 0; k0 < K; k0 += BK) {
        #pragma unroll
        for (int i = 0; i < 2; ++i) {
            const int idx = t + i * 256;       // 512 float4 slots per tile
            const int row = idx >> 3;
            const int f4  = idx & 7;
            float4 av = make_float4(0.f, 0.f, 0.f, 0.f);
            const int gm = m0 + row;
            if (gm < M) av = *(const float4*)&A[(size_t)gm * K + k0 + f4 * 4];
            bf16x4 ab;
            ab[0] = f2b(av.x); ab[1] = f2b(av.y); ab[2] = f2b(av.z); ab[3] = f2b(av.w);
            *(bf16x4*)&As[row][f4 * 4] = ab;
            const float4 wv = *(const float4*)&W[(size_t)(n0 + row) * K + k0 + f4 * 4];
            bf16x4 wb;
            wb[0] = f2b(wv.x); wb[1] = f2b(wv.y); wb[2] = f2b(wv.z); wb[3] = f2b(wv.w);
            *(bf16x4*)&Bs[row][f4 * 4] = wb;
        }
        __syncthreads();
        const bf16x8 af0 = *(const bf16x8*)&As[wr + fr][kg * 8];
        const bf16x8 af1 = *(const bf16x8*)&As[wr + 16 + fr][kg * 8];
        const bf16x8 bf0 = *(const bf16x8*)&Bs[wc + fr][kg * 8];
        const bf16x8 bf1 = *(const bf16x8*)&Bs[wc + 16 + fr][kg * 8];
        acc[0][0] = __builtin_amdgcn_mfma_f32_16x16x32_bf16(af0, bf0, acc[0][0], 0, 0, 0);
        acc[0][1] = __builtin_amdgcn_mfma_f32_16x16x32_bf16(af0, bf1, acc[0][1], 0, 0, 0);
        acc[1][0] = __builtin_amdgcn_mfma_f32_16x16x32_bf16(af1, bf0, acc[1][0], 0, 0, 0);
        acc[1][1] = __builtin_amdgcn_mfma_f32_16x16x32_bf16(af1, bf1, acc[1][1], 0, 0, 0);
        __syncthreads();
    }

    #pragma unroll
    for (int ti = 0; ti < 2; ++ti) {
        #pragma unroll
        for (int tj = 0; tj < 2; ++tj) {
            const int gn = n0 + wc + tj * 16 + fr;
            const float bv = bias[gn];
            #pragma unroll
            for (int v = 0; v < 4; ++v) {
                const int gm = m0 + wr + ti * 16 + kg * 4 + v;
                if (gm < M) {
                    float val = acc[ti][tj][v] + bv;
                    if (ACT == 1) val = gelu_exact(val);
                    if (RES) val += res[(size_t)gm * N + gn];
                    C[(size_t)gm * N + gn] = val;
                }
            }
        }
    }
}

// ---------------- kT[b][d][j] = qkv[b][j][D + d]  (32x32 LDS tiles) ----------------
__global__ void k_kT(const float* __restrict__ qkv, float* __restrict__ kT) {
    __shared__ float tile[32][33];
    const int b  = blockIdx.z;
    const int j0 = blockIdx.x * 32;
    const int d0 = blockIdx.y * 32;
    const int tx = threadIdx.x;
    const int ty = threadIdx.y;
    #pragma unroll
    for (int q = 0; q < 4; ++q) {
        const int j = j0 + ty + q * 8;
        if (j < LP1)
            tile[ty + q * 8][tx] = qkv[((size_t)(b * LP1 + j)) * (3 * D_) + D_ + d0 + tx];
    }
    __syncthreads();
    #pragma unroll
    for (int q = 0; q < 4; ++q) {
        const int j = j0 + tx;
        const int d = d0 + ty + q * 8;
        if (j < LP1)
            kT[((size_t)b * D_ + d) * LP1 + j] = tile[tx][ty + q * 8];
    }
}

// ---------------- attention core, QB=4 query tile per block ----------------
// group g (32 lanes) owns head g for all 4 queries; scores in registers;
// PV via __shfl broadcast (V row read once, reused for 4 queries).
__global__ __launch_bounds__(256)
void k_attn(const float* __restrict__ qkv, const float* __restrict__ kT,
            const float* __restrict__ s_norm, const float* __restrict__ table,
            float* __restrict__ a) {
    const int b   = blockIdx.x / QBLKS_;
    const int qi0 = (blockIdx.x % QBLKS_) * QB_;
    const int t = threadIdx.x;
    __shared__ float q_s[QB_][D_];
    __shared__ float s_s[LP1 + 1];

    for (int idx = t; idx < QB_ * D_; idx += 256) {
        const int q = idx >> 9;
        const int d = idx & 511;
        const int i = min(qi0 + q, LP1 - 1);
        q_s[q][d] = qkv[(size_t)(b * LP1 + i) * (3 * D_) + d];
    }
    for (int j = t; j < LP1; j += 256)
        s_s[j] = (j == 0) ? 0.f : s_norm[b * L_ + j - 1];
    __syncthreads();

    const int g  = t >> 5;    // head
    const int sl = t & 31;    // lane in group
    constexpr int NJ = 17;    // ceil(513/32)

    float s_i[QB_];
    #pragma unroll
    for (int q = 0; q < QB_; ++q) s_i[q] = s_s[min(qi0 + q, LP1 - 1)];

    // QK^T for 4 queries
    float acc[QB_][NJ] = {};
    const float* kTg = kT + ((size_t)b * D_ + g * HD_) * LP1;
    for (int dd = 0; dd < HD_; ++dd) {
        const float* row = kTg + (size_t)dd * LP1;
        float qv[QB_];
        #pragma unroll
        for (int q = 0; q < QB_; ++q) qv[q] = q_s[q][g * HD_ + dd];
        #pragma unroll
        for (int jj = 0; jj < NJ; ++jj) {
            const int j = sl + jj * 32;
            const float kv = (j < LP1) ? row[j] : 0.f;   // OOB stays inside ws: safe
            #pragma unroll
            for (int q = 0; q < QB_; ++q) acc[q][jj] = fmaf(qv[q], kv, acc[q][jj]);
        }
    }

    // bias lerp + softmax per query (scores stay in registers)
    #pragma unroll
    for (int q = 0; q < QB_; ++q) {
        float mx = -1e30f;
        #pragma unroll
        for (int jj = 0; jj < NJ; ++jj) {
            const int j = sl + jj * 32;
            if (j < LP1) {
                const float ds = s_i[q] - s_s[j];
                float u = (ds + 1.0f) * ((NT_ - 1) * 0.5f);
                u = fminf(fmaxf(u, 0.0f), (float)(NT_ - 2));
                const int i0 = (int)u;
                const float f = u - (float)i0;
                const float b0  = table[(size_t)i0 * H_ + g];
                const float b1v = table[(size_t)(i0 + 1) * H_ + g];
                acc[q][jj] = b0 + f * (b1v - b0) + 0.125f * acc[q][jj];
                mx = fmaxf(mx, acc[q][jj]);
            }
        }
        #pragma unroll
        for (int off = 16; off > 0; off >>= 1) mx = fmaxf(mx, __shfl_xor(mx, off, 32));
        float sum = 0.f;
        #pragma unroll
        for (int jj = 0; jj < NJ; ++jj) {
            const int j = sl + jj * 32;
            if (j < LP1) {
                acc[q][jj] = __expf(acc[q][jj] - mx);
                sum += acc[q][jj];
            }
        }
        #pragma unroll
        for (int off = 16; off > 0; off >>= 1) sum += __shfl_xor(sum, off, 32);
        const float inv = 1.0f / sum;
        #pragma unroll
        for (int jj = 0; jj < NJ; ++jj) acc[q][jj] *= inv;
    }

    // PV via shfl broadcast: V row read once per block, reused by all 4 queries.
    float o0[QB_] = {}, o1[QB_] = {};
    const float* vg = qkv + (size_t)(b * LP1) * (3 * D_) + 2 * D_ + g * HD_;
    #pragma unroll
    for (int jj = 0; jj < NJ; ++jj) {
        const int jmax = (jj == NJ - 1) ? (LP1 - 32 * (NJ - 1)) : 32;   // 1 or 32
        for (int src = 0; src < jmax; ++src) {
            const int j = jj * 32 + src;
            const float* vrow = vg + (size_t)j * (3 * D_);
            const float v0 = vrow[sl];
            const float v1 = vrow[sl + 32];
            #pragma unroll
            for (int q = 0; q < QB_; ++q) {
                const float pq = __shfl(acc[q][jj], src, 32);
                o0[q] = fmaf(pq, v0, o0[q]);
                o1[q] = fmaf(pq, v1, o1[q]);
            }
        }
    }

    #pragma unroll
    for (int q = 0; q < QB_; ++q) {
        const int i = qi0 + q;
        if (i < LP1) {
            a[(size_t)(b * LP1 + i) * D_ + g * HD_ + sl]      = o0[q];
            a[(size_t)(b * LP1 + i) * D_ + g * HD_ + sl + 32] = o1[q];
        }
    }
}

extern "C" void kernel_launch(void* const* d_in, const int* in_sizes, int n_in,
                              void* d_out, int out_size, void* d_ws, size_t ws_size,
                              hipStream_t stream) {
    const float* x      = (const float*)d_in[0];
    const float* s_norm = (const float*)d_in[1];
    const float* rff    = (const float*)d_in[2];
    const float* rb_w1  = (const float*)d_in[3];
    const float* rb_b1  = (const float*)d_in[4];
    const float* rb_w2  = (const float*)d_in[5];
    const float* rb_b2  = (const float*)d_in[6];
    const float* n1_g   = (const float*)d_in[7];
    const float* n1_b   = (const float*)d_in[8];
    const float* n2_g   = (const float*)d_in[9];
    const float* n2_b   = (const float*)d_in[10];
    const float* in_w   = (const float*)d_in[11];
    const float* in_b   = (const float*)d_in[12];
    const float* out_w  = (const float*)d_in[13];
    const float* out_b  = (const float*)d_in[14];
    const float* ff_w1  = (const float*)d_in[15];
    const float* ff_b1  = (const float*)d_in[16];
    const float* ff_w2  = (const float*)d_in[17];
    const float* ff_b2  = (const float*)d_in[18];

    float* ws    = (float*)d_ws;
    float* z     = ws + OFFZ;      // reused as h2
    float* x1    = ws + OFFX1;
    float* qkv   = ws + OFFQKV;
    float* kT    = ws + OFFKT;
    float* a     = ws + OFFA;
    float* table = ws + OFFT;
    float* h2    = z;
    float* hact  = qkv;            // overlays qkv+kT (both dead by FF phase)

    // 0) bias table
    k_btab<<<(NT_ + 255) / 256, 256, 0, stream>>>(rff, rb_w1, rb_b1, rb_w2, rb_b2, table);
    // 1) LN1 -> z
    k_ln<<<M_, 256, 0, stream>>>(x, n1_g, n1_b, z);
    // 2) qkv = z @ in_w^T + in_b
    k_gemm_mfma<0, false><<<dim3(3 * D_ / 64, (M_ + 63) / 64), 256, 0, stream>>>(
        z, in_w, in_b, nullptr, qkv, M_, 3 * D_, D_);
    // 3) kT = transpose of K part
    k_kT<<<dim3((LP1 + 31) / 32, D_ / 32, B_), dim3(32, 8), 0, stream>>>(qkv, kT);
    // 4) attention core (QB=4) -> a
    k_attn<<<B_ * QBLKS_, 256, 0, stream>>>(qkv, kT, s_norm, table, a);
    // 5) x1 = x + a @ out_w^T + out_b
    k_gemm_mfma<0, true><<<dim3(D_ / 64, (M_ + 63) / 64), 256, 0, stream>>>(
        a, out_w, out_b, x, x1, M_, D_, D_);
    // 6) LN2 -> h2
    k_ln<<<M_, 256, 0, stream>>>(x1, n2_g, n2_b, h2);
    // 7) hact = gelu(h2 @ ff_w1^T + ff_b1)
    k_gemm_mfma<1, false><<<dim3(FF_ / 64, (M_ + 63) / 64), 256, 0, stream>>>(
        h2, ff_w1, ff_b1, nullptr, hact, M_, FF_, D_);
    // 8) out = x1 + hact @ ff_w2^T + ff_b2
    k_gemm_mfma<0, true><<<dim3(D_ / 64, (M_ + 63) / 64), 256, 0, stream>>>(
        hact, ff_w2, ff_b2, x1, (float*)d_out, M_, D_, FF_);
}

// Round 13
// 339.019 us; speedup vs baseline: 7.0125x; 7.0125x over previous
//
#include <hip/hip_runtime.h>
#include <hip/hip_bf16.h>
#include <math.h>

// dims
constexpr int B_   = 2;
constexpr int L_   = 512;
constexpr int LP1  = 513;
constexpr int D_   = 512;
constexpr int H_   = 8;
constexpr int HD_  = 64;
constexpr int FF_  = 2048;
constexpr int RFFD = 32;
constexpr int RBH  = 64;
constexpr int M_   = B_ * LP1;     // 1026
constexpr float EPS_ = 1e-5f;
constexpr int NT_  = 8193;         // bias table entries over ds in [-1,1]
constexpr int QB_  = 2;            // queries per attention block (LDS scores)
constexpr int QBLKS_ = (LP1 + QB_ - 1) / QB_;   // 257

// ws layout (floats), overlays:
constexpr size_t OFFZ   = 0;
constexpr size_t OFFX1  = OFFZ  + (size_t)M_ * D_;          // 525,312
constexpr size_t OFFQKV = OFFX1 + (size_t)M_ * D_;          // 1,050,624
constexpr size_t OFFKT  = OFFQKV + (size_t)M_ * 3 * D_;     // 2,626,560
constexpr size_t OFFA   = OFFKT + (size_t)B_ * D_ * LP1;    // 3,151,872
constexpr size_t OFFT   = OFFA + (size_t)M_ * D_;           // 3,677,184
// + NT_*8 = 65,544 -> total 3,742,728 floats = 15.0 MB

typedef __attribute__((ext_vector_type(4))) float f32x4;
typedef __attribute__((ext_vector_type(8))) __bf16 bf16x8;
typedef __attribute__((ext_vector_type(4))) __bf16 bf16x4;

__device__ __forceinline__ float gelu_exact(float x) {
    return 0.5f * x * (1.0f + erff(x * 0.70710678118654752f));
}

__device__ __forceinline__ __bf16 f2b(float f) {
    union { float f; unsigned u; } a; a.f = f;
    const unsigned r = (a.u + 0x7FFFu + ((a.u >> 16) & 1u)) >> 16;   // RNE
    union { unsigned short s; __bf16 b; } o; o.s = (unsigned short)r;
    return o.b;
}

// ---------------- bias table: table[idx][h] = biasMLP(ds(idx))[h] ----------------
__global__ void k_btab(const float* __restrict__ rff, const float* __restrict__ w1,
                       const float* __restrict__ b1, const float* __restrict__ w2,
                       const float* __restrict__ b2, float* __restrict__ table) {
    const int idx = blockIdx.x * 256 + threadIdx.x;
    if (idx >= NT_) return;
    const float ds = (float)idx * (2.0f / (NT_ - 1)) - 1.0f;
    float feat[RFFD];
    #pragma unroll
    for (int k = 0; k < RFFD; ++k) feat[k] = sinf(ds * rff[k]);
    float bh[H_];
    #pragma unroll
    for (int h = 0; h < H_; ++h) bh[h] = b2[h];
    for (int l = 0; l < RBH; ++l) {
        float acc = b1[l];
        #pragma unroll
        for (int k = 0; k < RFFD; ++k) acc += feat[k] * w1[l * RFFD + k];
        const float gl = gelu_exact(acc);
        #pragma unroll
        for (int h = 0; h < H_; ++h) bh[h] += gl * w2[h * RBH + l];
    }
    #pragma unroll
    for (int h = 0; h < H_; ++h) table[(size_t)idx * H_ + h] = bh[h];
}

// ---------------- LayerNorm: one block (256) per token ----------------
__global__ void k_ln(const float* __restrict__ x, const float* __restrict__ g,
                     const float* __restrict__ be, float* __restrict__ out) {
    const int m = blockIdx.x;
    const int t = threadIdx.x;
    __shared__ float red[256];
    const float v0 = x[(size_t)m * D_ + t];
    const float v1 = x[(size_t)m * D_ + t + 256];
    red[t] = v0 + v1;
    __syncthreads();
    for (int off = 128; off > 0; off >>= 1) {
        if (t < off) red[t] += red[t + off];
        __syncthreads();
    }
    const float mu = red[0] * (1.0f / D_);
    __syncthreads();
    const float d0 = v0 - mu, d1 = v1 - mu;
    red[t] = d0 * d0 + d1 * d1;
    __syncthreads();
    for (int off = 128; off > 0; off >>= 1) {
        if (t < off) red[t] += red[t + off];
        __syncthreads();
    }
    const float rstd = rsqrtf(red[0] * (1.0f / D_) + EPS_);
    out[(size_t)m * D_ + t]       = d0 * rstd * g[t]       + be[t];
    out[(size_t)m * D_ + t + 256] = d1 * rstd * g[t + 256] + be[t + 256];
}

// ---------------- MFMA bf16 GEMM: C = act(A @ W^T + bias) (+res) ----------------
template <int ACT, bool RES>
__global__ __launch_bounds__(256)
void k_gemm_mfma(const float* __restrict__ A, const float* __restrict__ W,
                 const float* __restrict__ bias, const float* __restrict__ res,
                 float* __restrict__ C, int M, int N, int K) {
    constexpr int BM = 64, BN = 64, BK = 32, PAD = 8;   // row stride 80B (16B-aligned)
    __shared__ __bf16 As[BM][BK + PAD];
    __shared__ __bf16 Bs[BN][BK + PAD];
    const int t    = threadIdx.x;
    const int m0   = blockIdx.y * BM;
    const int n0   = blockIdx.x * BN;
    const int wid  = t >> 6;
    const int lane = t & 63;
    const int wr   = (wid >> 1) * 32;
    const int wc   = (wid & 1) * 32;
    const int fr   = lane & 15;
    const int kg   = lane >> 4;

    f32x4 acc[2][2] = {};

    for (int k0 = 0; k0 < K; k0 += BK) {
        #pragma unroll
        for (int i = 0; i < 2; ++i) {
            const int idx = t + i * 256;       // 512 float4 slots per tile
            const int row = idx >> 3;
            const int f4  = idx & 7;
            float4 av = make_float4(0.f, 0.f, 0.f, 0.f);
            const int gm = m0 + row;
            if (gm < M) av = *(const float4*)&A[(size_t)gm * K + k0 + f4 * 4];
            bf16x4 ab;
            ab[0] = f2b(av.x); ab[1] = f2b(av.y); ab[2] = f2b(av.z); ab[3] = f2b(av.w);
            *(bf16x4*)&As[row][f4 * 4] = ab;
            const float4 wv = *(const float4*)&W[(size_t)(n0 + row) * K + k0 + f4 * 4];
            bf16x4 wb;
            wb[0] = f2b(wv.x); wb[1] = f2b(wv.y); wb[2] = f2b(wv.z); wb[3] = f2b(wv.w);
            *(bf16x4*)&Bs[row][f4 * 4] = wb;
        }
        __syncthreads();
        const bf16x8 af0 = *(const bf16x8*)&As[wr + fr][kg * 8];
        const bf16x8 af1 = *(const bf16x8*)&As[wr + 16 + fr][kg * 8];
        const bf16x8 bf0 = *(const bf16x8*)&Bs[wc + fr][kg * 8];
        const bf16x8 bf1 = *(const bf16x8*)&Bs[wc + 16 + fr][kg * 8];
        acc[0][0] = __builtin_amdgcn_mfma_f32_16x16x32_bf16(af0, bf0, acc[0][0], 0, 0, 0);
        acc[0][1] = __builtin_amdgcn_mfma_f32_16x16x32_bf16(af0, bf1, acc[0][1], 0, 0, 0);
        acc[1][0] = __builtin_amdgcn_mfma_f32_16x16x32_bf16(af1, bf0, acc[1][0], 0, 0, 0);
        acc[1][1] = __builtin_amdgcn_mfma_f32_16x16x32_bf16(af1, bf1, acc[1][1], 0, 0, 0);
        __syncthreads();
    }

    #pragma unroll
    for (int ti = 0; ti < 2; ++ti) {
        #pragma unroll
        for (int tj = 0; tj < 2; ++tj) {
            const int gn = n0 + wc + tj * 16 + fr;
            const float bv = bias[gn];
            #pragma unroll
            for (int v = 0; v < 4; ++v) {
                const int gm = m0 + wr + ti * 16 + kg * 4 + v;
                if (gm < M) {
                    float val = acc[ti][tj][v] + bv;
                    if (ACT == 1) val = gelu_exact(val);
                    if (RES) val += res[(size_t)gm * N + gn];
                    C[(size_t)gm * N + gn] = val;
                }
            }
        }
    }
}

// ---------------- kT[b][d][j] = qkv[b][j][D + d]  (32x32 LDS tiles) ----------------
__global__ void k_kT(const float* __restrict__ qkv, float* __restrict__ kT) {
    __shared__ float tile[32][33];
    const int b  = blockIdx.z;
    const int j0 = blockIdx.x * 32;
    const int d0 = blockIdx.y * 32;
    const int tx = threadIdx.x;
    const int ty = threadIdx.y;
    #pragma unroll
    for (int q = 0; q < 4; ++q) {
        const int j = j0 + ty + q * 8;
        if (j < LP1)
            tile[ty + q * 8][tx] = qkv[((size_t)(b * LP1 + j)) * (3 * D_) + D_ + d0 + tx];
    }
    __syncthreads();
    #pragma unroll
    for (int q = 0; q < 4; ++q) {
        const int j = j0 + tx;
        const int d = d0 + ty + q * 8;
        if (j < LP1)
            kT[((size_t)b * D_ + d) * LP1 + j] = tile[tx][ty + q * 8];
    }
}

// ---------------- attention core, QB=2 queries per block, LDS scores ----------
// Structure identical to the proven R11 kernel; each per-block kT/V read is
// amortized over 2 queries. Scores live in registers only during QK (34 regs),
// probabilities pass through LDS to the PV phase (spill-safe).
__global__ __launch_bounds__(256)
void k_attn(const float* __restrict__ qkv, const float* __restrict__ kT,
            const float* __restrict__ s_norm, const float* __restrict__ table,
            float* __restrict__ a) {
    const int b   = blockIdx.x / QBLKS_;
    const int qi0 = (blockIdx.x % QBLKS_) * QB_;
    const int t = threadIdx.x;
    __shared__ float q_s[QB_][D_];
    __shared__ float s_s[LP1 + 1];
    __shared__ float p_s[QB_][H_][LP1 + 3];

    for (int idx = t; idx < QB_ * D_; idx += 256) {
        const int q = idx >> 9;
        const int d = idx & 511;
        const int i = min(qi0 + q, LP1 - 1);
        q_s[q][d] = qkv[(size_t)(b * LP1 + i) * (3 * D_) + d];
    }
    for (int j = t; j < LP1; j += 256)
        s_s[j] = (j == 0) ? 0.f : s_norm[b * L_ + j - 1];
    __syncthreads();

    const int g  = t >> 5;    // head
    const int sl = t & 31;    // lane in group
    constexpr int NJ = 17;    // ceil(513/32)

    float s_i[QB_];
    #pragma unroll
    for (int q = 0; q < QB_; ++q) s_i[q] = s_s[min(qi0 + q, LP1 - 1)];

    // QK^T for both queries (kT row read once, used twice)
    float acc[QB_][NJ] = {};
    const float* kTg = kT + ((size_t)b * D_ + g * HD_) * LP1;
    for (int dd = 0; dd < HD_; ++dd) {
        const float* row = kTg + (size_t)dd * LP1;
        float qv[QB_];
        #pragma unroll
        for (int q = 0; q < QB_; ++q) qv[q] = q_s[q][g * HD_ + dd];
        #pragma unroll
        for (int jj = 0; jj < NJ; ++jj) {
            const int j = sl + jj * 32;
            const float kv = (j < LP1) ? row[j] : 0.f;   // OOB stays inside ws: safe
            #pragma unroll
            for (int q = 0; q < QB_; ++q) acc[q][jj] = fmaf(qv[q], kv, acc[q][jj]);
        }
    }

    // bias lerp + softmax per query; probabilities -> LDS (ends acc live range)
    #pragma unroll
    for (int q = 0; q < QB_; ++q) {
        float mx = -1e30f;
        #pragma unroll
        for (int jj = 0; jj < NJ; ++jj) {
            const int j = sl + jj * 32;
            if (j < LP1) {
                const float ds = s_i[q] - s_s[j];
                float u = (ds + 1.0f) * ((NT_ - 1) * 0.5f);
                u = fminf(fmaxf(u, 0.0f), (float)(NT_ - 2));
                const int i0 = (int)u;
                const float f = u - (float)i0;
                const float b0  = table[(size_t)i0 * H_ + g];
                const float b1v = table[(size_t)(i0 + 1) * H_ + g];
                acc[q][jj] = b0 + f * (b1v - b0) + 0.125f * acc[q][jj];
                mx = fmaxf(mx, acc[q][jj]);
            }
        }
        #pragma unroll
        for (int off = 16; off > 0; off >>= 1) mx = fmaxf(mx, __shfl_xor(mx, off, 32));
        float sum = 0.f;
        #pragma unroll
        for (int jj = 0; jj < NJ; ++jj) {
            const int j = sl + jj * 32;
            if (j < LP1) {
                acc[q][jj] = __expf(acc[q][jj] - mx);
                sum += acc[q][jj];
            }
        }
        #pragma unroll
        for (int off = 16; off > 0; off >>= 1) sum += __shfl_xor(sum, off, 32);
        const float inv = 1.0f / sum;
        #pragma unroll
        for (int jj = 0; jj < NJ; ++jj) {
            const int j = sl + jj * 32;
            if (j < LP1) p_s[q][g][j] = acc[q][jj] * inv;
        }
    }
    __syncthreads();

    // PV: each V element read once per block, used by both queries; 2-way j ILP.
    const float* vbase = qkv + (size_t)(b * LP1) * (3 * D_) + 2 * D_;
    for (int e = t; e < D_; e += 256) {
        const int h = e >> 6;
        float o00 = 0.f, o01 = 0.f, o10 = 0.f, o11 = 0.f;
        int j = 0;
        for (; j + 2 <= LP1; j += 2) {
            const float v0 = vbase[(size_t)(j + 0) * (3 * D_) + e];
            const float v1 = vbase[(size_t)(j + 1) * (3 * D_) + e];
            o00 = fmaf(p_s[0][h][j + 0], v0, o00);
            o01 = fmaf(p_s[0][h][j + 1], v1, o01);
            o10 = fmaf(p_s[1][h][j + 0], v0, o10);
            o11 = fmaf(p_s[1][h][j + 1], v1, o11);
        }
        for (; j < LP1; ++j) {
            const float v0 = vbase[(size_t)j * (3 * D_) + e];
            o00 = fmaf(p_s[0][h][j], v0, o00);
            o10 = fmaf(p_s[1][h][j], v0, o10);
        }
        if (qi0 < LP1)
            a[(size_t)(b * LP1 + qi0) * D_ + e] = o00 + o01;
        if (qi0 + 1 < LP1)
            a[(size_t)(b * LP1 + qi0 + 1) * D_ + e] = o10 + o11;
    }
}

extern "C" void kernel_launch(void* const* d_in, const int* in_sizes, int n_in,
                              void* d_out, int out_size, void* d_ws, size_t ws_size,
                              hipStream_t stream) {
    const float* x      = (const float*)d_in[0];
    const float* s_norm = (const float*)d_in[1];
    const float* rff    = (const float*)d_in[2];
    const float* rb_w1  = (const float*)d_in[3];
    const float* rb_b1  = (const float*)d_in[4];
    const float* rb_w2  = (const float*)d_in[5];
    const float* rb_b2  = (const float*)d_in[6];
    const float* n1_g   = (const float*)d_in[7];
    const float* n1_b   = (const float*)d_in[8];
    const float* n2_g   = (const float*)d_in[9];
    const float* n2_b   = (const float*)d_in[10];
    const float* in_w   = (const float*)d_in[11];
    const float* in_b   = (const float*)d_in[12];
    const float* out_w  = (const float*)d_in[13];
    const float* out_b  = (const float*)d_in[14];
    const float* ff_w1  = (const float*)d_in[15];
    const float* ff_b1  = (const float*)d_in[16];
    const float* ff_w2  = (const float*)d_in[17];
    const float* ff_b2  = (const float*)d_in[18];

    float* ws    = (float*)d_ws;
    float* z     = ws + OFFZ;      // reused as h2
    float* x1    = ws + OFFX1;
    float* qkv   = ws + OFFQKV;
    float* kT    = ws + OFFKT;
    float* a     = ws + OFFA;
    float* table = ws + OFFT;
    float* h2    = z;
    float* hact  = qkv;            // overlays qkv+kT (both dead by FF phase)

    // 0) bias table
    k_btab<<<(NT_ + 255) / 256, 256, 0, stream>>>(rff, rb_w1, rb_b1, rb_w2, rb_b2, table);
    // 1) LN1 -> z
    k_ln<<<M_, 256, 0, stream>>>(x, n1_g, n1_b, z);
    // 2) qkv = z @ in_w^T + in_b
    k_gemm_mfma<0, false><<<dim3(3 * D_ / 64, (M_ + 63) / 64), 256, 0, stream>>>(
        z, in_w, in_b, nullptr, qkv, M_, 3 * D_, D_);
    // 3) kT = transpose of K part
    k_kT<<<dim3((LP1 + 31) / 32, D_ / 32, B_), dim3(32, 8), 0, stream>>>(qkv, kT);
    // 4) attention core (QB=2, LDS scores) -> a
    k_attn<<<B_ * QBLKS_, 256, 0, stream>>>(qkv, kT, s_norm, table, a);
    // 5) x1 = x + a @ out_w^T + out_b
    k_gemm_mfma<0, true><<<dim3(D_ / 64, (M_ + 63) / 64), 256, 0, stream>>>(
        a, out_w, out_b, x, x1, M_, D_, D_);
    // 6) LN2 -> h2
    k_ln<<<M_, 256, 0, stream>>>(x1, n2_g, n2_b, h2);
    // 7) hact = gelu(h2 @ ff_w1^T + ff_b1)
    k_gemm_mfma<1, false><<<dim3(FF_ / 64, (M_ + 63) / 64), 256, 0, stream>>>(
        h2, ff_w1, ff_b1, nullptr, hact, M_, FF_, D_);
    // 8) out = x1 + hact @ ff_w2^T + ff_b2
    k_gemm_mfma<0, true><<<dim3(D_ / 64, (M_ + 63) / 64), 256, 0, stream>>>(
        hact, ff_w2, ff_b2, x1, (float*)d_out, M_, D_, FF_);
}

// Round 14
// 299.194 us; speedup vs baseline: 7.9459x; 1.1331x over previous
//
#include <hip/hip_runtime.h>
#include <hip/hip_bf16.h>
#include <math.h>

// dims
constexpr int B_   = 2;
constexpr int L_   = 512;
constexpr int LP1  = 513;
constexpr int D_   = 512;
constexpr int H_   = 8;
constexpr int HD_  = 64;
constexpr int FF_  = 2048;
constexpr int RFFD = 32;
constexpr int RBH  = 64;
constexpr int M_   = B_ * LP1;     // 1026
constexpr float EPS_ = 1e-5f;
constexpr int NT_  = 8193;         // bias table entries over ds in [-1,1]
constexpr int QB_  = 2;            // queries per attention block (LDS scores)
constexpr int QBLKS_ = (LP1 + QB_ - 1) / QB_;   // 257

// ws layout (floats), overlays:
constexpr size_t OFFZ   = 0;
constexpr size_t OFFX1  = OFFZ  + (size_t)M_ * D_;          // 525,312
constexpr size_t OFFQKV = OFFX1 + (size_t)M_ * D_;          // 1,050,624
constexpr size_t OFFKT  = OFFQKV + (size_t)M_ * 3 * D_;     // 2,626,560
constexpr size_t OFFA   = OFFKT + (size_t)B_ * D_ * LP1;    // 3,151,872
constexpr size_t OFFT   = OFFA + (size_t)M_ * D_;           // 3,677,184
// + NT_*8 = 65,544 -> total 3,742,728 floats = 15.0 MB

typedef __attribute__((ext_vector_type(4))) float f32x4;
typedef __attribute__((ext_vector_type(8))) __bf16 bf16x8;
typedef __attribute__((ext_vector_type(4))) __bf16 bf16x4;

__device__ __forceinline__ float gelu_exact(float x) {
    return 0.5f * x * (1.0f + erff(x * 0.70710678118654752f));
}

__device__ __forceinline__ __bf16 f2b(float f) {
    union { float f; unsigned u; } a; a.f = f;
    const unsigned r = (a.u + 0x7FFFu + ((a.u >> 16) & 1u)) >> 16;   // RNE
    union { unsigned short s; __bf16 b; } o; o.s = (unsigned short)r;
    return o.b;
}

// ---------------- bias table: table[idx][h] = biasMLP(ds(idx))[h] ----------------
__global__ void k_btab(const float* __restrict__ rff, const float* __restrict__ w1,
                       const float* __restrict__ b1, const float* __restrict__ w2,
                       const float* __restrict__ b2, float* __restrict__ table) {
    const int idx = blockIdx.x * 256 + threadIdx.x;
    if (idx >= NT_) return;
    const float ds = (float)idx * (2.0f / (NT_ - 1)) - 1.0f;
    float feat[RFFD];
    #pragma unroll
    for (int k = 0; k < RFFD; ++k) feat[k] = sinf(ds * rff[k]);
    float bh[H_];
    #pragma unroll
    for (int h = 0; h < H_; ++h) bh[h] = b2[h];
    for (int l = 0; l < RBH; ++l) {
        float acc = b1[l];
        #pragma unroll
        for (int k = 0; k < RFFD; ++k) acc += feat[k] * w1[l * RFFD + k];
        const float gl = gelu_exact(acc);
        #pragma unroll
        for (int h = 0; h < H_; ++h) bh[h] += gl * w2[h * RBH + l];
    }
    #pragma unroll
    for (int h = 0; h < H_; ++h) table[(size_t)idx * H_ + h] = bh[h];
}

// ---------------- LayerNorm: one block (256) per token ----------------
__global__ void k_ln(const float* __restrict__ x, const float* __restrict__ g,
                     const float* __restrict__ be, float* __restrict__ out) {
    const int m = blockIdx.x;
    const int t = threadIdx.x;
    __shared__ float red[256];
    const float v0 = x[(size_t)m * D_ + t];
    const float v1 = x[(size_t)m * D_ + t + 256];
    red[t] = v0 + v1;
    __syncthreads();
    for (int off = 128; off > 0; off >>= 1) {
        if (t < off) red[t] += red[t + off];
        __syncthreads();
    }
    const float mu = red[0] * (1.0f / D_);
    __syncthreads();
    const float d0 = v0 - mu, d1 = v1 - mu;
    red[t] = d0 * d0 + d1 * d1;
    __syncthreads();
    for (int off = 128; off > 0; off >>= 1) {
        if (t < off) red[t] += red[t + off];
        __syncthreads();
    }
    const float rstd = rsqrtf(red[0] * (1.0f / D_) + EPS_);
    out[(size_t)m * D_ + t]       = d0 * rstd * g[t]       + be[t];
    out[(size_t)m * D_ + t + 256] = d1 * rstd * g[t + 256] + be[t + 256];
}

// ---- MFMA bf16 GEMM, 2-deep pipelined staging, dbuf LDS, 1 barrier/K-step ----
// BM=64: 4 waves in 2x2, each 32x32 quadrant (2x2 MFMA tiles).
// BM=32: 4 waves in 1x4, each 32x16 strip (2x1 MFMA tiles). Grid flattened + XCD swizzle.
template <int ACT, bool RES, int BM>
__global__ __launch_bounds__(256)
void k_gemm_mfma(const float* __restrict__ A, const float* __restrict__ W,
                 const float* __restrict__ bias, const float* __restrict__ res,
                 float* __restrict__ C, int M, int N, int K) {
    constexpr int BN = 64, BK = 32, PAD = 8;   // row stride 80B
    constexpr int LA = (BM * BK) / (4 * 256);  // A float4 per thread (1 or 2)
    constexpr int WRT = 2;
    constexpr int WCT = (BM == 64) ? 2 : 1;
    __shared__ __bf16 As[2][BM][BK + PAD];
    __shared__ __bf16 Bs[2][BN][BK + PAD];
    const int t = threadIdx.x;

    // bijective XCD swizzle (m204) on flattened grid
    const int nx = N / BN;
    int bid = blockIdx.x;
    {
        const int nb = gridDim.x;
        const int q = nb >> 3, r = nb & 7;
        const int xc = bid & 7, o = bid >> 3;
        bid = (xc < r ? xc * (q + 1) : r * (q + 1) + (xc - r) * q) + o;
    }
    const int m0 = (bid / nx) * BM;
    const int n0 = (bid % nx) * BN;

    const int wid  = t >> 6;
    const int lane = t & 63;
    const int wr   = (BM == 64) ? ((wid >> 1) * 32) : 0;
    const int wc   = (BM == 64) ? ((wid & 1) * 32) : (wid * 16);
    const int fr   = lane & 15;
    const int kg   = lane >> 4;
    const int lrow = t >> 3;     // loader row (0..31)
    const int lf4  = t & 7;      // loader float4 col

    f32x4 acc[WRT][WCT] = {};
    float4 pa[LA], pw[2];
    const int nk = K / BK;

    auto load_tile = [&](int kt) {
        const int kbase = kt * BK + lf4 * 4;
        #pragma unroll
        for (int i = 0; i < LA; ++i) {
            const int gm = m0 + lrow + i * 32;
            pa[i] = make_float4(0.f, 0.f, 0.f, 0.f);
            if (gm < M) pa[i] = *(const float4*)&A[(size_t)gm * K + kbase];
        }
        #pragma unroll
        for (int i = 0; i < 2; ++i)
            pw[i] = *(const float4*)&W[(size_t)(n0 + lrow + i * 32) * K + kbase];
    };
    auto store_tile = [&](int buf) {
        #pragma unroll
        for (int i = 0; i < LA; ++i) {
            bf16x4 v;
            v[0] = f2b(pa[i].x); v[1] = f2b(pa[i].y);
            v[2] = f2b(pa[i].z); v[3] = f2b(pa[i].w);
            *(bf16x4*)&As[buf][lrow + i * 32][lf4 * 4] = v;
        }
        #pragma unroll
        for (int i = 0; i < 2; ++i) {
            bf16x4 v;
            v[0] = f2b(pw[i].x); v[1] = f2b(pw[i].y);
            v[2] = f2b(pw[i].z); v[3] = f2b(pw[i].w);
            *(bf16x4*)&Bs[buf][lrow + i * 32][lf4 * 4] = v;
        }
    };

    load_tile(0);
    store_tile(0);
    __syncthreads();
    int cur = 0;
    for (int kt = 0; kt < nk; ++kt) {
        if (kt + 1 < nk) load_tile(kt + 1);          // issue next-tile loads early
        bf16x8 af[WRT], bfr[WCT];
        #pragma unroll
        for (int i2 = 0; i2 < WRT; ++i2)
            af[i2] = *(const bf16x8*)&As[cur][wr + i2 * 16 + fr][kg * 8];
        #pragma unroll
        for (int j2 = 0; j2 < WCT; ++j2)
            bfr[j2] = *(const bf16x8*)&Bs[cur][wc + j2 * 16 + fr][kg * 8];
        #pragma unroll
        for (int i2 = 0; i2 < WRT; ++i2)
            #pragma unroll
            for (int j2 = 0; j2 < WCT; ++j2)
                acc[i2][j2] = __builtin_amdgcn_mfma_f32_16x16x32_bf16(
                    af[i2], bfr[j2], acc[i2][j2], 0, 0, 0);
        if (kt + 1 < nk) store_tile(cur ^ 1);        // vmcnt wait hidden under MFMA
        __syncthreads();                             // single barrier per K-step
        cur ^= 1;
    }

    #pragma unroll
    for (int ti = 0; ti < WRT; ++ti) {
        #pragma unroll
        for (int tj = 0; tj < WCT; ++tj) {
            const int gn = n0 + wc + tj * 16 + fr;
            const float bv = bias[gn];
            #pragma unroll
            for (int v = 0; v < 4; ++v) {
                const int gm = m0 + wr + ti * 16 + kg * 4 + v;
                if (gm < M) {
                    float val = acc[ti][tj][v] + bv;
                    if (ACT == 1) val = gelu_exact(val);
                    if (RES) val += res[(size_t)gm * N + gn];
                    C[(size_t)gm * N + gn] = val;
                }
            }
        }
    }
}

// ---------------- kT[b][d][j] = qkv[b][j][D + d]  (32x32 LDS tiles) ----------------
__global__ void k_kT(const float* __restrict__ qkv, float* __restrict__ kT) {
    __shared__ float tile[32][33];
    const int b  = blockIdx.z;
    const int j0 = blockIdx.x * 32;
    const int d0 = blockIdx.y * 32;
    const int tx = threadIdx.x;
    const int ty = threadIdx.y;
    #pragma unroll
    for (int q = 0; q < 4; ++q) {
        const int j = j0 + ty + q * 8;
        if (j < LP1)
            tile[ty + q * 8][tx] = qkv[((size_t)(b * LP1 + j)) * (3 * D_) + D_ + d0 + tx];
    }
    __syncthreads();
    #pragma unroll
    for (int q = 0; q < 4; ++q) {
        const int j = j0 + tx;
        const int d = d0 + ty + q * 8;
        if (j < LP1)
            kT[((size_t)b * D_ + d) * LP1 + j] = tile[tx][ty + q * 8];
    }
}

// ---------------- attention core, QB=2 queries per block, LDS scores ----------
__global__ __launch_bounds__(256)
void k_attn(const float* __restrict__ qkv, const float* __restrict__ kT,
            const float* __restrict__ s_norm, const float* __restrict__ table,
            float* __restrict__ a) {
    const int b   = blockIdx.x / QBLKS_;
    const int qi0 = (blockIdx.x % QBLKS_) * QB_;
    const int t = threadIdx.x;
    __shared__ float q_s[QB_][D_];
    __shared__ float s_s[LP1 + 1];
    __shared__ float p_s[QB_][H_][LP1 + 3];

    for (int idx = t; idx < QB_ * D_; idx += 256) {
        const int q = idx >> 9;
        const int d = idx & 511;
        const int i = min(qi0 + q, LP1 - 1);
        q_s[q][d] = qkv[(size_t)(b * LP1 + i) * (3 * D_) + d];
    }
    for (int j = t; j < LP1; j += 256)
        s_s[j] = (j == 0) ? 0.f : s_norm[b * L_ + j - 1];
    __syncthreads();

    const int g  = t >> 5;    // head
    const int sl = t & 31;    // lane in group
    constexpr int NJ = 17;    // ceil(513/32)

    float s_i[QB_];
    #pragma unroll
    for (int q = 0; q < QB_; ++q) s_i[q] = s_s[min(qi0 + q, LP1 - 1)];

    float acc[QB_][NJ] = {};
    const float* kTg = kT + ((size_t)b * D_ + g * HD_) * LP1;
    for (int dd = 0; dd < HD_; ++dd) {
        const float* row = kTg + (size_t)dd * LP1;
        float qv[QB_];
        #pragma unroll
        for (int q = 0; q < QB_; ++q) qv[q] = q_s[q][g * HD_ + dd];
        #pragma unroll
        for (int jj = 0; jj < NJ; ++jj) {
            const int j = sl + jj * 32;
            const float kv = (j < LP1) ? row[j] : 0.f;   // OOB stays inside ws: safe
            #pragma unroll
            for (int q = 0; q < QB_; ++q) acc[q][jj] = fmaf(qv[q], kv, acc[q][jj]);
        }
    }

    #pragma unroll
    for (int q = 0; q < QB_; ++q) {
        float mx = -1e30f;
        #pragma unroll
        for (int jj = 0; jj < NJ; ++jj) {
            const int j = sl + jj * 32;
            if (j < LP1) {
                const float ds = s_i[q] - s_s[j];
                float u = (ds + 1.0f) * ((NT_ - 1) * 0.5f);
                u = fminf(fmaxf(u, 0.0f), (float)(NT_ - 2));
                const int i0 = (int)u;
                const float f = u - (float)i0;
                const float b0  = table[(size_t)i0 * H_ + g];
                const float b1v = table[(size_t)(i0 + 1) * H_ + g];
                acc[q][jj] = b0 + f * (b1v - b0) + 0.125f * acc[q][jj];
                mx = fmaxf(mx, acc[q][jj]);
            }
        }
        #pragma unroll
        for (int off = 16; off > 0; off >>= 1) mx = fmaxf(mx, __shfl_xor(mx, off, 32));
        float sum = 0.f;
        #pragma unroll
        for (int jj = 0; jj < NJ; ++jj) {
            const int j = sl + jj * 32;
            if (j < LP1) {
                acc[q][jj] = __expf(acc[q][jj] - mx);
                sum += acc[q][jj];
            }
        }
        #pragma unroll
        for (int off = 16; off > 0; off >>= 1) sum += __shfl_xor(sum, off, 32);
        const float inv = 1.0f / sum;
        #pragma unroll
        for (int jj = 0; jj < NJ; ++jj) {
            const int j = sl + jj * 32;
            if (j < LP1) p_s[q][g][j] = acc[q][jj] * inv;
        }
    }
    __syncthreads();

    const float* vbase = qkv + (size_t)(b * LP1) * (3 * D_) + 2 * D_;
    for (int e = t; e < D_; e += 256) {
        const int h = e >> 6;
        float o00 = 0.f, o01 = 0.f, o10 = 0.f, o11 = 0.f;
        int j = 0;
        for (; j + 2 <= LP1; j += 2) {
            const float v0 = vbase[(size_t)(j + 0) * (3 * D_) + e];
            const float v1 = vbase[(size_t)(j + 1) * (3 * D_) + e];
            o00 = fmaf(p_s[0][h][j + 0], v0, o00);
            o01 = fmaf(p_s[0][h][j + 1], v1, o01);
            o10 = fmaf(p_s[1][h][j + 0], v0, o10);
            o11 = fmaf(p_s[1][h][j + 1], v1, o11);
        }
        for (; j < LP1; ++j) {
            const float v0 = vbase[(size_t)j * (3 * D_) + e];
            o00 = fmaf(p_s[0][h][j], v0, o00);
            o10 = fmaf(p_s[1][h][j], v0, o10);
        }
        if (qi0 < LP1)
            a[(size_t)(b * LP1 + qi0) * D_ + e] = o00 + o01;
        if (qi0 + 1 < LP1)
            a[(size_t)(b * LP1 + qi0 + 1) * D_ + e] = o10 + o11;
    }
}

extern "C" void kernel_launch(void* const* d_in, const int* in_sizes, int n_in,
                              void* d_out, int out_size, void* d_ws, size_t ws_size,
                              hipStream_t stream) {
    const float* x      = (const float*)d_in[0];
    const float* s_norm = (const float*)d_in[1];
    const float* rff    = (const float*)d_in[2];
    const float* rb_w1  = (const float*)d_in[3];
    const float* rb_b1  = (const float*)d_in[4];
    const float* rb_w2  = (const float*)d_in[5];
    const float* rb_b2  = (const float*)d_in[6];
    const float* n1_g   = (const float*)d_in[7];
    const float* n1_b   = (const float*)d_in[8];
    const float* n2_g   = (const float*)d_in[9];
    const float* n2_b   = (const float*)d_in[10];
    const float* in_w   = (const float*)d_in[11];
    const float* in_b   = (const float*)d_in[12];
    const float* out_w  = (const float*)d_in[13];
    const float* out_b  = (const float*)d_in[14];
    const float* ff_w1  = (const float*)d_in[15];
    const float* ff_b1  = (const float*)d_in[16];
    const float* ff_w2  = (const float*)d_in[17];
    const float* ff_b2  = (const float*)d_in[18];

    float* ws    = (float*)d_ws;
    float* z     = ws + OFFZ;      // reused as h2
    float* x1    = ws + OFFX1;
    float* qkv   = ws + OFFQKV;
    float* kT    = ws + OFFKT;
    float* a     = ws + OFFA;
    float* table = ws + OFFT;
    float* h2    = z;
    float* hact  = qkv;            // overlays qkv+kT (both dead by FF phase)

    // 0) bias table
    k_btab<<<(NT_ + 255) / 256, 256, 0, stream>>>(rff, rb_w1, rb_b1, rb_w2, rb_b2, table);
    // 1) LN1 -> z
    k_ln<<<M_, 256, 0, stream>>>(x, n1_g, n1_b, z);
    // 2) qkv = z @ in_w^T + in_b   (BM=64, 24x17=408 blocks)
    k_gemm_mfma<0, false, 64><<<(3 * D_ / 64) * ((M_ + 63) / 64), 256, 0, stream>>>(
        z, in_w, in_b, nullptr, qkv, M_, 3 * D_, D_);
    // 3) kT = transpose of K part
    k_kT<<<dim3((LP1 + 31) / 32, D_ / 32, B_), dim3(32, 8), 0, stream>>>(qkv, kT);
    // 4) attention core (QB=2, LDS scores) -> a
    k_attn<<<B_ * QBLKS_, 256, 0, stream>>>(qkv, kT, s_norm, table, a);
    // 5) x1 = x + a @ out_w^T + out_b   (BM=32, 8x33=264 blocks)
    k_gemm_mfma<0, true, 32><<<(D_ / 64) * ((M_ + 31) / 32), 256, 0, stream>>>(
        a, out_w, out_b, x, x1, M_, D_, D_);
    // 6) LN2 -> h2
    k_ln<<<M_, 256, 0, stream>>>(x1, n2_g, n2_b, h2);
    // 7) hact = gelu(h2 @ ff_w1^T + ff_b1)   (BM=64, 32x17=544 blocks)
    k_gemm_mfma<1, false, 64><<<(FF_ / 64) * ((M_ + 63) / 64), 256, 0, stream>>>(
        h2, ff_w1, ff_b1, nullptr, hact, M_, FF_, D_);
    // 8) out = x1 + hact @ ff_w2^T + ff_b2   (BM=32, 8x33=264 blocks)
    k_gemm_mfma<0, true, 32><<<(D_ / 64) * ((M_ + 31) / 32), 256, 0, stream>>>(
        hact, ff_w2, ff_b2, x1, (float*)d_out, M_, D_, FF_);
}

// Round 15
// 293.017 us; speedup vs baseline: 8.1134x; 1.0211x over previous
//
#include <hip/hip_runtime.h>
#include <hip/hip_bf16.h>
#include <math.h>

// dims
constexpr int B_   = 2;
constexpr int L_   = 512;
constexpr int LP1  = 513;
constexpr int D_   = 512;
constexpr int H_   = 8;
constexpr int HD_  = 64;
constexpr int FF_  = 2048;
constexpr int RFFD = 32;
constexpr int RBH  = 64;
constexpr int M_   = B_ * LP1;     // 1026
constexpr float EPS_ = 1e-5f;
constexpr int NT_  = 8193;         // bias table entries over ds in [-1,1]
constexpr int QB_  = 4;            // queries per attention block
constexpr int QT_  = (LP1 + QB_ - 1) / QB_;     // 129 query tiles

// ws layout (f32 slots), overlays:
constexpr size_t OFFZ   = 0;
constexpr size_t OFFX1  = OFFZ  + (size_t)M_ * D_;          // 525,312
constexpr size_t OFFQKV = OFFX1 + (size_t)M_ * D_;          // 1,050,624
constexpr size_t OFFKT  = OFFQKV + (size_t)M_ * 3 * D_;     // 2,626,560
constexpr size_t OFFA   = OFFKT + (size_t)B_ * D_ * LP1;    // 3,151,872
constexpr size_t OFFT   = OFFA + (size_t)M_ * D_;           // 3,677,184
constexpr size_t OFFWB  = OFFT + (size_t)NT_ * H_;          // 3,742,728 (bf16 weights)
// bf16 weight region: 3,145,728 bf16 = 1,572,864 slots -> total 5,315,592 f32 = 21.3 MB

typedef __attribute__((ext_vector_type(4))) float f32x4;
typedef __attribute__((ext_vector_type(8))) __bf16 bf16x8;
typedef __attribute__((ext_vector_type(4))) __bf16 bf16x4;

__device__ __forceinline__ float gelu_exact(float x) {
    return 0.5f * x * (1.0f + erff(x * 0.70710678118654752f));
}

__device__ __forceinline__ __bf16 f2b(float f) {
    union { float f; unsigned u; } a; a.f = f;
    const unsigned r = (a.u + 0x7FFFu + ((a.u >> 16) & 1u)) >> 16;   // RNE
    union { unsigned short s; __bf16 b; } o; o.s = (unsigned short)r;
    return o.b;
}

__device__ __forceinline__ bf16x8 bzero8() {
    bf16x8 v;
    #pragma unroll
    for (int i = 0; i < 8; ++i) v[i] = (__bf16)0.0f;
    return v;
}

// ---------------- weight f32 -> bf16 convert ----------------
__global__ void k_w2b(const float* __restrict__ src, __bf16* __restrict__ dst, int n) {
    const int i = (blockIdx.x * 256 + threadIdx.x) * 4;
    if (i < n) {
        const float4 v = *(const float4*)&src[i];
        bf16x4 o;
        o[0] = f2b(v.x); o[1] = f2b(v.y); o[2] = f2b(v.z); o[3] = f2b(v.w);
        *(bf16x4*)&dst[i] = o;
    }
}

// ---------------- bias table ----------------
__global__ void k_btab(const float* __restrict__ rff, const float* __restrict__ w1,
                       const float* __restrict__ b1, const float* __restrict__ w2,
                       const float* __restrict__ b2, float* __restrict__ table) {
    const int idx = blockIdx.x * 256 + threadIdx.x;
    if (idx >= NT_) return;
    const float ds = (float)idx * (2.0f / (NT_ - 1)) - 1.0f;
    float feat[RFFD];
    #pragma unroll
    for (int k = 0; k < RFFD; ++k) feat[k] = sinf(ds * rff[k]);
    float bh[H_];
    #pragma unroll
    for (int h = 0; h < H_; ++h) bh[h] = b2[h];
    for (int l = 0; l < RBH; ++l) {
        float acc = b1[l];
        #pragma unroll
        for (int k = 0; k < RFFD; ++k) acc += feat[k] * w1[l * RFFD + k];
        const float gl = gelu_exact(acc);
        #pragma unroll
        for (int h = 0; h < H_; ++h) bh[h] += gl * w2[h * RBH + l];
    }
    #pragma unroll
    for (int h = 0; h < H_; ++h) table[(size_t)idx * H_ + h] = bh[h];
}

// ---------------- LayerNorm ----------------
__global__ void k_ln(const float* __restrict__ x, const float* __restrict__ g,
                     const float* __restrict__ be, float* __restrict__ out) {
    const int m = blockIdx.x;
    const int t = threadIdx.x;
    __shared__ float red[256];
    const float v0 = x[(size_t)m * D_ + t];
    const float v1 = x[(size_t)m * D_ + t + 256];
    red[t] = v0 + v1;
    __syncthreads();
    for (int off = 128; off > 0; off >>= 1) {
        if (t < off) red[t] += red[t + off];
        __syncthreads();
    }
    const float mu = red[0] * (1.0f / D_);
    __syncthreads();
    const float d0 = v0 - mu, d1 = v1 - mu;
    red[t] = d0 * d0 + d1 * d1;
    __syncthreads();
    for (int off = 128; off > 0; off >>= 1) {
        if (t < off) red[t] += red[t + off];
        __syncthreads();
    }
    const float rstd = rsqrtf(red[0] * (1.0f / D_) + EPS_);
    out[(size_t)m * D_ + t]       = d0 * rstd * g[t]       + be[t];
    out[(size_t)m * D_ + t + 256] = d1 * rstd * g[t + 256] + be[t + 256];
}

// ---- MFMA bf16 GEMM, bf16 weights, 2-deep pipeline, dbuf LDS, 1 barrier/K-step ----
// AT = activation type (float or __bf16), OT = output type (float or __bf16).
template <int ACT, bool RES, int BM, typename AT, typename OT>
__global__ __launch_bounds__(256)
void k_gemm_mfma(const AT* __restrict__ A, const __bf16* __restrict__ W,
                 const float* __restrict__ bias, const float* __restrict__ res,
                 OT* __restrict__ C, int M, int N, int K) {
    constexpr int BN = 64, BK = 32, PAD = 8;   // bf16 row stride 80B
    constexpr bool ABF = (sizeof(AT) == 2);
    constexpr int LA = (BM * BK) / (4 * 256);  // float4/thread for f32 A (1 or 2)
    constexpr int WRT = 2;
    constexpr int WCT = (BM == 64) ? 2 : 1;
    __shared__ __bf16 As[2][BM][BK + PAD];
    __shared__ __bf16 Bs[2][BN][BK + PAD];
    const int t = threadIdx.x;

    // bijective XCD swizzle (m204) on flattened grid
    const int nx = N / BN;
    int bid = blockIdx.x;
    {
        const int nb = gridDim.x;
        const int q = nb >> 3, r = nb & 7;
        const int xc = bid & 7, o = bid >> 3;
        bid = (xc < r ? xc * (q + 1) : r * (q + 1) + (xc - r) * q) + o;
    }
    const int m0 = (bid / nx) * BM;
    const int n0 = (bid % nx) * BN;

    const int wid  = t >> 6;
    const int lane = t & 63;
    const int wr   = (BM == 64) ? ((wid >> 1) * 32) : 0;
    const int wc   = (BM == 64) ? ((wid & 1) * 32) : (wid * 16);
    const int fr   = lane & 15;
    const int kg   = lane >> 4;

    f32x4 acc[WRT][WCT] = {};
    float4 pa[LA > 0 ? LA : 1];
    bf16x8 pab, pwb;
    const int nk = K / BK;

    auto load_tile = [&](int kt) {
        const int kb = kt * BK;
        if constexpr (!ABF) {
            const int lrow = t >> 3, lf4 = t & 7;
            #pragma unroll
            for (int i = 0; i < LA; ++i) {
                const int gm = m0 + lrow + i * 32;
                pa[i] = make_float4(0.f, 0.f, 0.f, 0.f);
                if (gm < M) pa[i] = *(const float4*)&A[(size_t)gm * K + kb + lf4 * 4];
            }
        } else {
            const int lrow = t >> 2, lkc = t & 3;
            if (BM == 64 || t < 128) {
                const int gm = m0 + lrow;
                pab = (gm < M) ? *(const bf16x8*)&A[(size_t)gm * K + kb + lkc * 8]
                               : bzero8();
            }
        }
        {
            const int lrow = t >> 2, lkc = t & 3;
            pwb = *(const bf16x8*)&W[(size_t)(n0 + lrow) * K + kb + lkc * 8];
        }
    };
    auto store_tile = [&](int buf) {
        if constexpr (!ABF) {
            const int lrow = t >> 3, lf4 = t & 7;
            #pragma unroll
            for (int i = 0; i < LA; ++i) {
                bf16x4 v;
                v[0] = f2b(pa[i].x); v[1] = f2b(pa[i].y);
                v[2] = f2b(pa[i].z); v[3] = f2b(pa[i].w);
                *(bf16x4*)&As[buf][lrow + i * 32][lf4 * 4] = v;
            }
        } else {
            const int lrow = t >> 2, lkc = t & 3;
            if (BM == 64 || t < 128) *(bf16x8*)&As[buf][lrow][lkc * 8] = pab;
        }
        {
            const int lrow = t >> 2, lkc = t & 3;
            *(bf16x8*)&Bs[buf][lrow][lkc * 8] = pwb;
        }
    };

    load_tile(0);
    store_tile(0);
    __syncthreads();
    int cur = 0;
    for (int kt = 0; kt < nk; ++kt) {
        if (kt + 1 < nk) load_tile(kt + 1);          // issue next-tile loads early
        bf16x8 af[WRT], bfr[WCT];
        #pragma unroll
        for (int i2 = 0; i2 < WRT; ++i2)
            af[i2] = *(const bf16x8*)&As[cur][wr + i2 * 16 + fr][kg * 8];
        #pragma unroll
        for (int j2 = 0; j2 < WCT; ++j2)
            bfr[j2] = *(const bf16x8*)&Bs[cur][wc + j2 * 16 + fr][kg * 8];
        #pragma unroll
        for (int i2 = 0; i2 < WRT; ++i2)
            #pragma unroll
            for (int j2 = 0; j2 < WCT; ++j2)
                acc[i2][j2] = __builtin_amdgcn_mfma_f32_16x16x32_bf16(
                    af[i2], bfr[j2], acc[i2][j2], 0, 0, 0);
        if (kt + 1 < nk) store_tile(cur ^ 1);        // vmcnt wait hidden under MFMA
        __syncthreads();                             // single barrier per K-step
        cur ^= 1;
    }

    #pragma unroll
    for (int ti = 0; ti < WRT; ++ti) {
        #pragma unroll
        for (int tj = 0; tj < WCT; ++tj) {
            const int gn = n0 + wc + tj * 16 + fr;
            const float bv = bias[gn];
            #pragma unroll
            for (int v = 0; v < 4; ++v) {
                const int gm = m0 + wr + ti * 16 + kg * 4 + v;
                if (gm < M) {
                    float val = acc[ti][tj][v] + bv;
                    if (ACT == 1) val = gelu_exact(val);
                    if (RES) val += res[(size_t)gm * N + gn];
                    if constexpr (sizeof(OT) == 2) C[(size_t)gm * N + gn] = f2b(val);
                    else                           C[(size_t)gm * N + gn] = val;
                }
            }
        }
    }
}

// ---------------- kT[b][d][j] = qkv[b][j][D + d] ----------------
__global__ void k_kT(const float* __restrict__ qkv, float* __restrict__ kT) {
    __shared__ float tile[32][33];
    const int b  = blockIdx.z;
    const int j0 = blockIdx.x * 32;
    const int d0 = blockIdx.y * 32;
    const int tx = threadIdx.x;
    const int ty = threadIdx.y;
    #pragma unroll
    for (int q = 0; q < 4; ++q) {
        const int j = j0 + ty + q * 8;
        if (j < LP1)
            tile[ty + q * 8][tx] = qkv[((size_t)(b * LP1 + j)) * (3 * D_) + D_ + d0 + tx];
    }
    __syncthreads();
    #pragma unroll
    for (int q = 0; q < 4; ++q) {
        const int j = j0 + tx;
        const int d = d0 + ty + q * 8;
        if (j < LP1)
            kT[((size_t)b * D_ + d) * LP1 + j] = tile[tx][ty + q * 8];
    }
}

// ---------------- attention core: 4 queries x 4 heads per block ----------------
// block = (b, query-tile, head-half). 8 groups of 32 lanes: group g handles
// head hh*4+(g>>1), query pair g&1. Scores in regs during QK (34), LDS after.
__global__ __launch_bounds__(256)
void k_attn(const float* __restrict__ qkv, const float* __restrict__ kT,
            const float* __restrict__ s_norm, const float* __restrict__ table,
            float* __restrict__ a) {
    const int hh  = blockIdx.x & 1;
    const int qt  = (blockIdx.x >> 1) % QT_;
    const int b   = blockIdx.x / (2 * QT_);
    const int qi0 = qt * QB_;
    const int t = threadIdx.x;
    __shared__ float q_s[QB_][256];
    __shared__ float s_s[LP1 + 1];
    __shared__ float p_s[QB_][4][LP1 + 3];

    for (int idx = t; idx < QB_ * 256; idx += 256) {
        const int q = idx >> 8;
        const int dl = idx & 255;
        const int i = min(qi0 + q, LP1 - 1);
        q_s[q][dl] = qkv[(size_t)(b * LP1 + i) * (3 * D_) + hh * 256 + dl];
    }
    for (int j = t; j < LP1; j += 256)
        s_s[j] = (j == 0) ? 0.f : s_norm[b * L_ + j - 1];
    __syncthreads();

    const int g   = t >> 5;
    const int sl  = t & 31;
    const int hl  = g >> 1;            // local head 0..3
    const int hid = hh * 4 + hl;       // global head
    const int qp  = g & 1;             // query pair (2 queries)
    constexpr int NJ = 17;

    float s_i[2];
    #pragma unroll
    for (int q2 = 0; q2 < 2; ++q2)
        s_i[q2] = s_s[min(qi0 + qp * 2 + q2, LP1 - 1)];

    // QK^T for 2 queries over this group's head (kT row read once, used twice)
    float acc[2][NJ] = {};
    const float* kTg = kT + ((size_t)b * D_ + hid * HD_) * LP1;
    for (int dd = 0; dd < HD_; ++dd) {
        const float* row = kTg + (size_t)dd * LP1;
        float qv[2];
        #pragma unroll
        for (int q2 = 0; q2 < 2; ++q2) qv[q2] = q_s[qp * 2 + q2][hl * 64 + dd];
        #pragma unroll
        for (int jj = 0; jj < NJ; ++jj) {
            const int j = sl + jj * 32;
            const float kv = (j < LP1) ? row[j] : 0.f;   // OOB stays inside ws: safe
            #pragma unroll
            for (int q2 = 0; q2 < 2; ++q2) acc[q2][jj] = fmaf(qv[q2], kv, acc[q2][jj]);
        }
    }

    // bias lerp + softmax; probabilities -> LDS
    #pragma unroll
    for (int q2 = 0; q2 < 2; ++q2) {
        float mx = -1e30f;
        #pragma unroll
        for (int jj = 0; jj < NJ; ++jj) {
            const int j = sl + jj * 32;
            if (j < LP1) {
                const float ds = s_i[q2] - s_s[j];
                float u = (ds + 1.0f) * ((NT_ - 1) * 0.5f);
                u = fminf(fmaxf(u, 0.0f), (float)(NT_ - 2));
                const int i0 = (int)u;
                const float f = u - (float)i0;
                const float b0  = table[(size_t)i0 * H_ + hid];
                const float b1v = table[(size_t)(i0 + 1) * H_ + hid];
                acc[q2][jj] = b0 + f * (b1v - b0) + 0.125f * acc[q2][jj];
                mx = fmaxf(mx, acc[q2][jj]);
            }
        }
        #pragma unroll
        for (int off = 16; off > 0; off >>= 1) mx = fmaxf(mx, __shfl_xor(mx, off, 32));
        float sum = 0.f;
        #pragma unroll
        for (int jj = 0; jj < NJ; ++jj) {
            const int j = sl + jj * 32;
            if (j < LP1) {
                acc[q2][jj] = __expf(acc[q2][jj] - mx);
                sum += acc[q2][jj];
            }
        }
        #pragma unroll
        for (int off = 16; off > 0; off >>= 1) sum += __shfl_xor(sum, off, 32);
        const float inv = 1.0f / sum;
        #pragma unroll
        for (int jj = 0; jj < NJ; ++jj) {
            const int j = sl + jj * 32;
            if (j < LP1) p_s[qp * 2 + q2][hl][j] = acc[q2][jj] * inv;
        }
    }
    __syncthreads();

    // PV: thread t owns output dim hh*256+t; V column read once, used by 4 queries.
    const int hl2 = t >> 6;
    const float* vbase = qkv + (size_t)(b * LP1) * (3 * D_) + 2 * D_ + hh * 256;
    float o0 = 0.f, o1 = 0.f, o2 = 0.f, o3 = 0.f;
    int j = 0;
    for (; j + 2 <= LP1; j += 2) {
        const float v0 = vbase[(size_t)(j + 0) * (3 * D_) + t];
        const float v1 = vbase[(size_t)(j + 1) * (3 * D_) + t];
        o0 = fmaf(p_s[0][hl2][j], v0, o0); o0 = fmaf(p_s[0][hl2][j + 1], v1, o0);
        o1 = fmaf(p_s[1][hl2][j], v0, o1); o1 = fmaf(p_s[1][hl2][j + 1], v1, o1);
        o2 = fmaf(p_s[2][hl2][j], v0, o2); o2 = fmaf(p_s[2][hl2][j + 1], v1, o2);
        o3 = fmaf(p_s[3][hl2][j], v0, o3); o3 = fmaf(p_s[3][hl2][j + 1], v1, o3);
    }
    for (; j < LP1; ++j) {
        const float v0 = vbase[(size_t)j * (3 * D_) + t];
        o0 = fmaf(p_s[0][hl2][j], v0, o0);
        o1 = fmaf(p_s[1][hl2][j], v0, o1);
        o2 = fmaf(p_s[2][hl2][j], v0, o2);
        o3 = fmaf(p_s[3][hl2][j], v0, o3);
    }
    const float oq[4] = {o0, o1, o2, o3};
    #pragma unroll
    for (int q = 0; q < QB_; ++q) {
        const int i = qi0 + q;
        if (i < LP1) a[(size_t)(b * LP1 + i) * D_ + hh * 256 + t] = oq[q];
    }
}

extern "C" void kernel_launch(void* const* d_in, const int* in_sizes, int n_in,
                              void* d_out, int out_size, void* d_ws, size_t ws_size,
                              hipStream_t stream) {
    const float* x      = (const float*)d_in[0];
    const float* s_norm = (const float*)d_in[1];
    const float* rff    = (const float*)d_in[2];
    const float* rb_w1  = (const float*)d_in[3];
    const float* rb_b1  = (const float*)d_in[4];
    const float* rb_w2  = (const float*)d_in[5];
    const float* rb_b2  = (const float*)d_in[6];
    const float* n1_g   = (const float*)d_in[7];
    const float* n1_b   = (const float*)d_in[8];
    const float* n2_g   = (const float*)d_in[9];
    const float* n2_b   = (const float*)d_in[10];
    const float* in_w   = (const float*)d_in[11];
    const float* in_b   = (const float*)d_in[12];
    const float* out_w  = (const float*)d_in[13];
    const float* out_b  = (const float*)d_in[14];
    const float* ff_w1  = (const float*)d_in[15];
    const float* ff_b1  = (const float*)d_in[16];
    const float* ff_w2  = (const float*)d_in[17];
    const float* ff_b2  = (const float*)d_in[18];

    float* ws    = (float*)d_ws;
    float* z     = ws + OFFZ;      // reused as h2
    float* x1    = ws + OFFX1;
    float* qkv   = ws + OFFQKV;
    float* kT    = ws + OFFKT;
    float* a     = ws + OFFA;
    float* table = ws + OFFT;
    float* h2    = z;
    __bf16* hactb = (__bf16*)qkv;  // overlays qkv (dead by FF phase), 4.2 MB

    __bf16* wb      = (__bf16*)(ws + OFFWB);
    __bf16* in_wb   = wb;                                  // 786,432
    __bf16* out_wb  = in_wb  + (size_t)3 * D_ * D_;        // 262,144
    __bf16* ff_w1b  = out_wb + (size_t)D_ * D_;            // 1,048,576
    __bf16* ff_w2b  = ff_w1b + (size_t)FF_ * D_;           // 1,048,576

    // 0a) weights -> bf16
    k_w2b<<<(3 * D_ * D_ / 4 + 255) / 256, 256, 0, stream>>>(in_w, in_wb, 3 * D_ * D_);
    k_w2b<<<(D_ * D_ / 4 + 255) / 256, 256, 0, stream>>>(out_w, out_wb, D_ * D_);
    k_w2b<<<(FF_ * D_ / 4 + 255) / 256, 256, 0, stream>>>(ff_w1, ff_w1b, FF_ * D_);
    k_w2b<<<(D_ * FF_ / 4 + 255) / 256, 256, 0, stream>>>(ff_w2, ff_w2b, D_ * FF_);
    // 0b) bias table
    k_btab<<<(NT_ + 255) / 256, 256, 0, stream>>>(rff, rb_w1, rb_b1, rb_w2, rb_b2, table);
    // 1) LN1 -> z
    k_ln<<<M_, 256, 0, stream>>>(x, n1_g, n1_b, z);
    // 2) qkv = z @ in_w^T + in_b
    k_gemm_mfma<0, false, 64, float, float>
        <<<(3 * D_ / 64) * ((M_ + 63) / 64), 256, 0, stream>>>(
        z, in_wb, in_b, nullptr, qkv, M_, 3 * D_, D_);
    // 3) kT = transpose of K part
    k_kT<<<dim3((LP1 + 31) / 32, D_ / 32, B_), dim3(32, 8), 0, stream>>>(qkv, kT);
    // 4) attention core (4q x 4h per block, 516 blocks) -> a
    k_attn<<<B_ * QT_ * 2, 256, 0, stream>>>(qkv, kT, s_norm, table, a);
    // 5) x1 = x + a @ out_w^T + out_b
    k_gemm_mfma<0, true, 32, float, float>
        <<<(D_ / 64) * ((M_ + 31) / 32), 256, 0, stream>>>(
        a, out_wb, out_b, x, x1, M_, D_, D_);
    // 6) LN2 -> h2
    k_ln<<<M_, 256, 0, stream>>>(x1, n2_g, n2_b, h2);
    // 7) hactb = gelu(h2 @ ff_w1^T + ff_b1)  [bf16 out]
    k_gemm_mfma<1, false, 64, float, __bf16>
        <<<(FF_ / 64) * ((M_ + 63) / 64), 256, 0, stream>>>(
        h2, ff_w1b, ff_b1, nullptr, hactb, M_, FF_, D_);
    // 8) out = x1 + hactb @ ff_w2^T + ff_b2  [bf16 A]
    k_gemm_mfma<0, true, 32, __bf16, float>
        <<<(D_ / 64) * ((M_ + 31) / 32), 256, 0, stream>>>(
        hactb, ff_w2b, ff_b2, x1, (float*)d_out, M_, D_, FF_);
}